// Round 7
// baseline (72.043 us; speedup 1.0000x reference)
//
#include <hip/hip_runtime.h>
#include <hip/hip_bf16.h>

// Problem constants (fixed by the reference)
#define NUM_WORDS 200000
#define EMBED 128
#define BATCH 16384
#define WIN 8
#define B_PER_BLK 8
#define GRID (BATCH / B_PER_BLK)   // 2048 blocks

typedef __attribute__((ext_vector_type(8))) short short8;   // 8 bf16 in 4 VGPRs
typedef __attribute__((ext_vector_type(4))) float f32x4;

#define LN_HALF (-0.69314718056f)

__device__ __forceinline__ short f2bf(float f) {
  unsigned u = __float_as_uint(f);
  u = u + 0x7FFFu + ((u >> 16) & 1u);   // round-to-nearest-even
  return (short)(u >> 16);
}

__device__ __forceinline__ short8 pack8(float4 a0, float4 a1) {
  short8 r;
  r[0] = f2bf(a0.x); r[1] = f2bf(a0.y); r[2] = f2bf(a0.z); r[3] = f2bf(a0.w);
  r[4] = f2bf(a1.x); r[5] = f2bf(a1.y); r[6] = f2bf(a1.z); r[7] = f2bf(a1.w);
  return r;
}

__device__ __forceinline__ float sp(float x) {   // stable softplus (for dots)
  return fmaxf(x, 0.f) + __logf(1.f + __expf(-fabsf(x)));
}

// ---------------------------------------------------------------------------
// Fused kernel.
// Phase 1: K=256 MFMA matvec  w_pre = [in_w[idx], cov_w[cov]] @ lin_w^T
//          (B-fragments packed on the fly from L1-resident lin_w; no prep).
// Row pass: wave wv owns rows {wv, wv+4} (32 lanes each) -> w_s rows become
//          wave-private -> NO second __syncthreads; waves destagger.
// Phase 2: 8 lanes per (b,w) row, line-exact mapping, 16-float4 preload.
// Linear loss terms accumulate per-thread; only dots use shuffles.
// ---------------------------------------------------------------------------
__global__ __launch_bounds__(256, 4) void main_kernel(
    const int* __restrict__ inputs, const int* __restrict__ outputs,
    const int* __restrict__ covars, const int* __restrict__ noise,
    const float* __restrict__ wtp,
    const float* __restrict__ eps_in, const float* __restrict__ eps_out,
    const float* __restrict__ in_w, const float* __restrict__ out_w,
    const float* __restrict__ in_rho_w, const float* __restrict__ out_rho_w,
    const float* __restrict__ cov_w, const float* __restrict__ lin_w,
    const float* __restrict__ lin_b,
    double* __restrict__ parts) {
  __shared__ float w_s[B_PER_BLK][132];   // w_pre, then w_in (padded stride)
  __shared__ float red_s[4];

  const int tid  = threadIdx.x;
  const int lane = tid & 63;
  const int wv   = tid >> 6;
  const int q    = lane >> 4;
  const int f16  = lane & 15;
  const int bbase = blockIdx.x * B_PER_BLK;
  const float wtv = wtp[0];

  // -------- early: phase-2 gather indices (in flight through phase 1) ------
  const int g  = tid >> 3;             // row group 0..31
  const int f8 = tid & 7;              // lane in group
  const int rA = bbase * 8 + g;        // it=0 row: b_global = bbase + wv
  const int rB = rA + 32;              // it=1 row: b_global = bbase + wv + 4
  const int oA = outputs[rA], nzA = noise[rA];
  const int oB = outputs[rB], nzB = noise[rB];

  // -------- phase 1: K=256 MFMA, A = [in_w[idx], cov_w[cov]], B = lin_w^T ---
  {
    const int bsel = f16 & (B_PER_BLK - 1);
    const int idxA = inputs[bbase + bsel];
    const int covA = covars[bbase + bsel];
    const float* ar0 = in_w  + (size_t)idxA * 128 + q * 8;   // k = 0..127
    const float* ar1 = cov_w + covA * 128 + q * 8;           // k = 128..255
    // B fragment: lane reads lin_w[j][k8..k8+8], j = wv*32 + jt*16 + f16
    const float* bptr = lin_w + (size_t)(wv * 32 + f16) * 256 + q * 8;

    f32x4 acc0 = {0.f, 0.f, 0.f, 0.f}, acc1 = {0.f, 0.f, 0.f, 0.f};
    #pragma unroll
    for (int kk = 0; kk < 8; ++kk) {
      const float* ap = (kk < 4) ? (ar0 + kk * 32) : (ar1 + (kk - 4) * 32);
      float4 a0  = *(const float4*)ap;
      float4 a1  = *(const float4*)(ap + 4);
      float4 b00 = *(const float4*)(bptr + kk * 32);
      float4 b01 = *(const float4*)(bptr + kk * 32 + 4);
      float4 b10 = *(const float4*)(bptr + 16 * 256 + kk * 32);
      float4 b11 = *(const float4*)(bptr + 16 * 256 + kk * 32 + 4);
      short8 af = pack8(a0, a1);
      acc0 = __builtin_amdgcn_mfma_f32_16x16x32_bf16(af, pack8(b00, b01), acc0, 0, 0, 0);
      acc1 = __builtin_amdgcn_mfma_f32_16x16x32_bf16(af, pack8(b10, b11), acc1, 0, 0, 0);
    }
    // D: lane holds D[b = q*4+r][j = wv*32 + jt*16 + f16]; keep rows < 8
    #pragma unroll
    for (int r = 0; r < 4; ++r) {
      int row = q * 4 + r;
      if (row < B_PER_BLK) {
        w_s[row][wv * 32 + f16]      = acc0[r];
        w_s[row][wv * 32 + 16 + f16] = acc1[r];
      }
    }
  }
  __syncthreads();   // MFMA D-writes are cross-wave; after this, rows go wave-private

  float accum = 0.f;

  // -------- row pass: wave wv owns rows {wv, wv+4}, 32 lanes x 4 elems ------
  {
    const int h  = lane >> 5;            // half-wave
    const int b  = wv + 4 * h;           // wave-private row
    const int jj = (lane & 31) * 4;
    const int gb = bbase + b;
    const int idx = inputs[gb];

    float4 wp = *(const float4*)(&w_s[b][jj]);
    float4 rh = *(const float4*)(in_rho_w + (size_t)idx * 128 + jj);
    float4 ep = *(const float4*)(eps_in + (size_t)gb * 128 + jj);
    float4 lb = *(const float4*)(lin_b + jj);

    float rha[4] = {rh.x, rh.y, rh.z, rh.w};
    float epa[4] = {ep.x, ep.y, ep.z, ep.w};
    float xa[4]  = {wp.x + lb.x, wp.y + lb.y, wp.z + lb.z, wp.w + lb.w};

    float wi4[4];
    float se2 = 0.f, sw2 = 0.f, ps = 1.f, pu = 1.f;
    #pragma unroll
    for (int e = 0; e < 4; ++e) {
      float es = __expf(rha[e]);          // rho in (-1,1): no overflow
      float s  = __logf(1.f + es);        // softplus
      float x  = fminf(fmaxf(xa[e], -15.f), 15.f);
      float e2 = __expf(2.f * x);
      float th = (e2 - 1.f) / (e2 + 1.f);
      float w  = th + s * epa[e];
      wi4[e] = w;
      float u  = __expf(-12.f * w * w);
      ps *= s; pu *= (1.f + u);
      se2 += epa[e] * epa[e];
      sw2 += w * w;
    }
    // publish w_in (same-wave consumers only; no barrier needed)
    *(float4*)(&w_s[b][jj]) = make_float4(wi4[0], wi4[1], wi4[2], wi4[3]);
    // post_in - prior_in slice, linear -> per-thread accumulate (x8 windows)
    float t1 = -0.5f * se2 - __logf(ps) + 0.5f * sw2 - 4.f * LN_HALF - __logf(pu);
    accum = 8.f * wtv * t1;
  }
  asm volatile("" ::: "memory");   // keep w_s publish before phase-2 reads

  // -------- phase 2: 8 lanes per row, line-exact, full register preload -----
  {
    #pragma unroll
    for (int it = 0; it < 2; ++it) {
      const int o  = it ? oB : oA;
      const int nz = it ? nzB : nzA;
      const int r  = it ? rB : rA;
      const int b2 = it ? (wv + 4) : wv;     // wave-uniform w_s row
      const float* wrow = out_w     + (size_t)o  * 128;
      const float* rrow = out_rho_w + (size_t)o  * 128;
      const float* erow = eps_out   + (size_t)r  * 128;
      const float* nrow = out_w     + (size_t)nz * 128;

      float4 mo[4], ro[4], eo[4], nv[4];
      #pragma unroll
      for (int c = 0; c < 4; ++c) {
        const int off = (c * 8 + f8) * 4;    // 8 lanes -> one full 128B line
        mo[c] = *(const float4*)(wrow + off);
        ro[c] = *(const float4*)(rrow + off);
        eo[c] = *(const float4*)(erow + off);
        nv[c] = *(const float4*)(nrow + off);
      }

      float d1 = 0.f, d2 = 0.f, se2 = 0.f, sw2 = 0.f;
      float ps = 1.f, pu = 1.f;

      #pragma unroll
      for (int c = 0; c < 4; ++c) {
        const int off = (c * 8 + f8) * 4;
        float4 wi = *(const float4*)(&w_s[b2][off]);
        float moa[4] = {mo[c].x, mo[c].y, mo[c].z, mo[c].w};
        float roa[4] = {ro[c].x, ro[c].y, ro[c].z, ro[c].w};
        float eoa[4] = {eo[c].x, eo[c].y, eo[c].z, eo[c].w};
        float nva[4] = {nv[c].x, nv[c].y, nv[c].z, nv[c].w};
        float wia[4] = {wi.x, wi.y, wi.z, wi.w};

        #pragma unroll
        for (int e = 0; e < 4; ++e) {
          float es = __expf(roa[e]);       // rho in (-1,1)
          float s  = __logf(1.f + es);
          float wo = fmaf(s, eoa[e], moa[e]);
          float u  = __expf(-12.f * wo * wo);
          ps *= s;
          pu *= (1.f + u);
          se2 += eoa[e] * eoa[e];
          sw2 += wo * wo;
          d1  += wia[e] * wo;
          d2  += wia[e] * nva[e];
        }
      }
      // linear part: wt * (post_out - prior_out) slice (16 elems)
      float t2 = -0.5f * se2 - __logf(ps) + 0.5f * sw2 - 16.f * LN_HALF - __logf(pu);
      accum += wtv * t2;

      // full-row dots: reduce over the 8-lane group
      d1 += __shfl_xor(d1, 1, 64); d1 += __shfl_xor(d1, 2, 64); d1 += __shfl_xor(d1, 4, 64);
      d2 += __shfl_xor(d2, 1, 64); d2 += __shfl_xor(d2, 2, 64); d2 += __shfl_xor(d2, 4, 64);
      if (f8 == 0) accum += sp(-d1) + sp(d2);   // -log_target - log_sampled
    }
  }

  // -------- deterministic block reduction ----------------------------------
  #pragma unroll
  for (int m = 1; m <= 32; m <<= 1) accum += __shfl_xor(accum, m, 64);
  if (lane == 0) red_s[wv] = accum;
  __syncthreads();
  if (tid == 0) {
    double s = (double)red_s[0] + (double)red_s[1] + (double)red_s[2] + (double)red_s[3];
    parts[blockIdx.x] = s;
  }
}

// ---------------------------------------------------------------------------
// Final deterministic reduction: block partials -> mean
// ---------------------------------------------------------------------------
__global__ void fin_kernel(const double* __restrict__ parts, float* __restrict__ out) {
  __shared__ double s[256];
  const int tid = threadIdx.x;
  double a = 0.0;
  for (int i = tid; i < GRID; i += 256) a += parts[i];
  s[tid] = a;
  __syncthreads();
  for (int st = 128; st > 0; st >>= 1) {
    if (tid < st) s[tid] += s[tid + st];
    __syncthreads();
  }
  if (tid == 0) out[0] = (float)(s[0] / (double)(BATCH * WIN));
}

extern "C" void kernel_launch(void* const* d_in, const int* in_sizes, int n_in,
                              void* d_out, int out_size, void* d_ws, size_t ws_size,
                              hipStream_t stream) {
  const int*   inputs    = (const int*)d_in[0];
  const int*   outputs   = (const int*)d_in[1];
  const int*   covars    = (const int*)d_in[2];
  const int*   noise     = (const int*)d_in[3];
  const float* wt        = (const float*)d_in[4];
  const float* eps_in    = (const float*)d_in[5];
  const float* eps_out   = (const float*)d_in[6];
  const float* in_w      = (const float*)d_in[7];
  const float* out_w     = (const float*)d_in[8];
  const float* in_rho_w  = (const float*)d_in[9];
  const float* out_rho_w = (const float*)d_in[10];
  const float* cov_w     = (const float*)d_in[11];
  const float* lin_w     = (const float*)d_in[12];
  const float* lin_b     = (const float*)d_in[13];

  double* parts = (double*)d_ws;                           // 16384 B

  main_kernel<<<GRID, 256, 0, stream>>>(inputs, outputs, covars, noise, wt,
                                        eps_in, eps_out, in_w, out_w,
                                        in_rho_w, out_rho_w, cov_w, lin_w,
                                        lin_b, parts);
  fin_kernel<<<1, 256, 0, stream>>>(parts, (float*)d_out);
}